// Round 15
// baseline (11146.004 us; speedup 1.0000x reference)
//
#include <hip/hip_runtime.h>
#include <hip/hip_bf16.h>
#include <math.h>

#define Bn 64
#define Tn 2048
#define Hn 256

constexpr float LEAK    = 0.5f;     // 1 - 1/TAU
constexpr float NEGDIAG = -0.5f;    // -1/TAU
constexpr float CLAMP_V = 1000.0f;
constexpr float EPS_V   = 1e-4f;

typedef __attribute__((ext_vector_type(8))) short  short8;  // 8 bf16 (4 VGPR)
typedef __attribute__((ext_vector_type(4))) float  f32x4;
typedef __attribute__((ext_vector_type(2))) float  f32x2;

#define FAST_BARRIER() do {                                   \
    asm volatile("s_waitcnt lgkmcnt(0)" ::: "memory");        \
    __builtin_amdgcn_s_barrier();                             \
    asm volatile("" ::: "memory");                            \
  } while (0)

__device__ inline short bf16_rne(float x) {
  __hip_bfloat16 h = __float2bfloat16(x);
  return *reinterpret_cast<short*>(&h);
}
__device__ inline float bf16_to_f(short s) {
  union { unsigned u; float f; } c; c.u = ((unsigned)(unsigned short)s) << 16;
  return c.f;
}
__device__ inline unsigned pack2(short a, short b) {
  return (unsigned)(unsigned short)a | ((unsigned)(unsigned short)b << 16);
}
// packed dual fp32 FMA: a += x*y
__device__ inline void pkfma(f32x2& a, f32x2 x, f32x2 y) {
  asm("v_pk_fma_f32 %0, %1, %2, %0" : "+v"(a) : "v"(x), "v"(y));
}
#define SWZ(x, imm) __int_as_float(__builtin_amdgcn_ds_swizzle(__float_as_int(x), (imm)))

// DPP receive: value of `x` from the DPP-selected partner lane (VALU pipe)
template <int CTRL>
__device__ __forceinline__ float dpp_recv(float x) {
  return __int_as_float(
      __builtin_amdgcn_update_dpp(0, __float_as_int(x), CTRL, 0xF, 0xF, true));
}

// LDS row stride for bf16 tiles: 32 k + 8 pad = 40 shorts (80 B, 16B-multiple)
#define SA 40

// ---------------------------------------------------------------------------
// G1: u = relu(inp8 @ W1^T + b1) @ Wih^T, MFMA bf16 hi/lo. (unchanged, passing)
// ---------------------------------------------------------------------------
__global__ __launch_bounds__(512) void g_u(
    const float* __restrict__ reward, const float* __restrict__ state,
    const float* __restrict__ last_action, const float* __restrict__ W1,
    const float* __restrict__ b1, const float* __restrict__ Wih,
    float* __restrict__ u)
{
  __shared__ short Ah[128*SA], Al[128*SA], Bh[256*SA], Bl[256*SA];
  __shared__ __align__(16) float inp_s[128][8];
  __shared__ __align__(16) float w1_s[256][8];
  __shared__ float b1_s[256];
  const int tid = threadIdx.x;
  const int r0  = blockIdx.x * 128;

  for (int idx = tid; idx < 2048; idx += 512) ((float*)w1_s)[idx] = W1[idx];
  if (tid < 256) b1_s[tid] = b1[tid];
  for (int idx = tid; idx < 1024; idx += 512) {
    int rr = idx >> 3, i = idx & 7;
    int r = r0 + rr, b = r & 63, t = r >> 6;
    long base = (long)b * Tn + t;
    float v;
    if (i < 2)      v = reward[base * 2 + i];
    else if (i < 6) v = state[base * 4 + (i - 2)];
    else            v = last_action[base * 2 + (i - 6)];
    inp_s[rr][i] = v;
  }

  const int w    = tid >> 6, lane = tid & 63;
  const int wm   = w >> 2, wn = w & 3;
  const int fr   = lane & 15, fk = lane >> 4;
  f32x4 acc[4][4];
  #pragma unroll
  for (int a = 0; a < 4; ++a)
    #pragma unroll
    for (int c = 0; c < 4; ++c) acc[a][c] = (f32x4){0.f, 0.f, 0.f, 0.f};

  __syncthreads();

  for (int ks = 0; ks < 8; ++ks) {
    const int k0 = ks * 32;
    if (ks) __syncthreads();
    for (int p = tid; p < 2048; p += 512) {
      int rr = p >> 4, kp = (p & 15) * 2;
      int k = k0 + kp;
      float4 iv0 = *reinterpret_cast<const float4*>(&inp_s[rr][0]);
      float4 iv1 = *reinterpret_cast<const float4*>(&inp_s[rr][4]);
      float4 wa0 = *reinterpret_cast<const float4*>(&w1_s[k][0]);
      float4 wa1 = *reinterpret_cast<const float4*>(&w1_s[k][4]);
      float4 wb0 = *reinterpret_cast<const float4*>(&w1_s[k+1][0]);
      float4 wb1 = *reinterpret_cast<const float4*>(&w1_s[k+1][4]);
      float s0 = b1_s[k], s1 = b1_s[k+1];
      s0 = fmaf(iv0.x, wa0.x, s0); s0 = fmaf(iv0.y, wa0.y, s0);
      s0 = fmaf(iv0.z, wa0.z, s0); s0 = fmaf(iv0.w, wa0.w, s0);
      s0 = fmaf(iv1.x, wa1.x, s0); s0 = fmaf(iv1.y, wa1.y, s0);
      s0 = fmaf(iv1.z, wa1.z, s0); s0 = fmaf(iv1.w, wa1.w, s0);
      s1 = fmaf(iv0.x, wb0.x, s1); s1 = fmaf(iv0.y, wb0.y, s1);
      s1 = fmaf(iv0.z, wb0.z, s1); s1 = fmaf(iv0.w, wb0.w, s1);
      s1 = fmaf(iv1.x, wb1.x, s1); s1 = fmaf(iv1.y, wb1.y, s1);
      s1 = fmaf(iv1.z, wb1.z, s1); s1 = fmaf(iv1.w, wb1.w, s1);
      float v0 = fmaxf(s0, 0.f), v1 = fmaxf(s1, 0.f);
      short h0 = bf16_rne(v0), h1 = bf16_rne(v1);
      short l0 = bf16_rne(v0 - bf16_to_f(h0)), l1 = bf16_rne(v1 - bf16_to_f(h1));
      int off = rr * SA + kp;
      *reinterpret_cast<unsigned*>(&Ah[off]) = pack2(h0, h1);
      *reinterpret_cast<unsigned*>(&Al[off]) = pack2(l0, l1);
    }
    for (int c = tid; c < 2048; c += 512) {
      int n = c >> 3, kc = (c & 7) * 4;
      float4 f = *reinterpret_cast<const float4*>(&Wih[n * 256 + k0 + kc]);
      short h0 = bf16_rne(f.x), h1 = bf16_rne(f.y), h2 = bf16_rne(f.z), h3 = bf16_rne(f.w);
      short l0 = bf16_rne(f.x - bf16_to_f(h0)), l1 = bf16_rne(f.y - bf16_to_f(h1));
      short l2 = bf16_rne(f.z - bf16_to_f(h2)), l3 = bf16_rne(f.w - bf16_to_f(h3));
      int off = n * SA + kc;
      *reinterpret_cast<uint2*>(&Bh[off]) = make_uint2(pack2(h0, h1), pack2(h2, h3));
      *reinterpret_cast<uint2*>(&Bl[off]) = make_uint2(pack2(l0, l1), pack2(l2, l3));
    }
    __syncthreads();
    short8 bhf[4], blf[4];
    #pragma unroll
    for (int nf = 0; nf < 4; ++nf) {
      const int brow = wn * 64 + nf * 16 + fr;
      bhf[nf] = *reinterpret_cast<const short8*>(&Bh[brow * SA + fk * 8]);
      blf[nf] = *reinterpret_cast<const short8*>(&Bl[brow * SA + fk * 8]);
    }
    #pragma unroll
    for (int mf = 0; mf < 4; ++mf) {
      const int arow = wm * 64 + mf * 16 + fr;
      short8 ah = *reinterpret_cast<const short8*>(&Ah[arow * SA + fk * 8]);
      short8 al = *reinterpret_cast<const short8*>(&Al[arow * SA + fk * 8]);
      #pragma unroll
      for (int nf = 0; nf < 4; ++nf) {
        acc[mf][nf] = __builtin_amdgcn_mfma_f32_16x16x32_bf16(ah, bhf[nf], acc[mf][nf], 0, 0, 0);
        acc[mf][nf] = __builtin_amdgcn_mfma_f32_16x16x32_bf16(ah, blf[nf], acc[mf][nf], 0, 0, 0);
        acc[mf][nf] = __builtin_amdgcn_mfma_f32_16x16x32_bf16(al, bhf[nf], acc[mf][nf], 0, 0, 0);
      }
    }
  }
  #pragma unroll
  for (int mf = 0; mf < 4; ++mf) {
    const int rbase = r0 + wm * 64 + mf * 16 + (lane >> 4) * 4;
    #pragma unroll
    for (int nf = 0; nf < 4; ++nf) {
      const int n = wn * 64 + nf * 16 + fr;
      #pragma unroll
      for (int j = 0; j < 4; ++j)
        u[(long)(rbase + j) * Hn + n] = acc[mf][nf][j];
    }
  }
}

// ---------------------------------------------------------------------------
// K2 v14: TWO batches per block. 1024 thr = 16 waves; half hw = tid>>9 runs
// batch 2*bid+hw with the EXACT r7/r9/r13-verified per-half code (8 waves,
// XOR-keyed slots, DPP+swizzle+permlane reduce, 2-step u rotation), its own
// rh[hw] double-buffer and u/ys pointers. Halves share only the block
// barrier (identical step counts -> benign). Doubles waves/SIMD 2->4 so the
// ~1200 cyc/step latency stall (VALUBusy was only 17%) overlaps across 2x
// the waves. Worst case step time unchanged -> total unchanged.
// ---------------------------------------------------------------------------
__global__ __launch_bounds__(1024, 4) void k_scan(
    const float* __restrict__ Whh_raw, const float* __restrict__ hidden_in,
    float* __restrict__ ubuf, float* __restrict__ out)
{
  __shared__ __align__(16) float rh[2][2][256];   // [half][buf][256]
  const int tid = threadIdx.x;
  const int hw = tid >> 9;                      // batch half 0/1
  const int w = (tid >> 6) & 7;                 // wave within half, 0..7
  const int l = tid & 63;
  const int g = (l & 3) | ((l >> 1) & 0x1C);    // k-group: bits {0,1,3,4,5}
  const int o = (l >> 2) & 1;                   // output half
  const int b = (blockIdx.x << 1) + hw;
  // XOR key = bitrev4(g&15): slot s holds output m = s ^ key
  const int key = ((g & 1) << 3) | ((g & 2) << 1) | ((g & 4) >> 1) | ((g & 8) >> 3);

  // weights: slot s, pair i -> output j = 32w+16o+(s^key), k = 8g+2i(+1)
  f32x2 w2[16][4];
  #pragma unroll
  for (int s = 0; s < 16; ++s) {
    const int j = (w << 5) + (o << 4) + (s ^ key);
    #pragma unroll
    for (int i = 0; i < 4; ++i) {
      const int k = (g << 3) + 2 * i;
      float a = Whh_raw[j * 256 + k];
      float c = Whh_raw[j * 256 + k + 1];
      if (k == j)     a = NEGDIAG;
      if (k + 1 == j) c = NEGDIAG;
      w2[s][i] = (f32x2){a, c};
    }
  }

  const bool owner = (l < 32);
  const int j_own = (w << 5) + (o << 4) + key;

  // swizzle: logical k stored at row*32 + ((k&31) + 4*row)&31, row = k>>5
  const int row  = g >> 2;
  const int srot = (((g & 3) << 3) + (row << 2)) & 31;
  const int rd1  = row * 32 + srot;
  const int rd2  = row * 32 + ((srot + 4) & 31);
  const int wrow = j_own >> 5;
  const int wr   = wrow * 32 + (((j_own & 31) + (wrow << 2)) & 31);

  float (&rhh)[2][256] = rh[hw];

  float h = 0.f, u_c = 0.f, u_n = 0.f;
  if (owner) {
    h   = hidden_in[b * Hn + j_own];
    u_c = ubuf[(long)b * Hn + j_own];                    // u[t=0]
    u_n = ubuf[((long)Bn + b) * Hn + j_own];             // u[t=1]
  }
  const float* u_ptr  = ubuf + ((long)2 * Bn + b) * Hn + j_own;   // t = 2
  float*       ys_ptr = ubuf + (long)b * Hn + j_own;              // t = 0

#define SCAN_STEP(P)                                                         \
  {                                                                          \
    if (owner) rhh[P][wr] = fmaxf(h, 0.f);                                   \
    FAST_BARRIER();                                                          \
    float u_pf = 0.f;                                                        \
    if (owner && t + 2 < Tn) u_pf = *u_ptr;                                  \
    const float4 ra = *reinterpret_cast<const float4*>(&rhh[P][rd1]);        \
    const float4 rb = *reinterpret_cast<const float4*>(&rhh[P][rd2]);        \
    const f32x2 rp0 = {ra.x, ra.y}, rp1 = {ra.z, ra.w};                      \
    const f32x2 rp2 = {rb.x, rb.y}, rp3 = {rb.z, rb.w};                      \
    float v[16];                                                             \
    _Pragma("unroll")                                                        \
    for (int s = 0; s < 16; ++s) {                                           \
      f32x2 c = {0.f, 0.f};                                                  \
      pkfma(c, rp0, w2[s][0]); pkfma(c, rp1, w2[s][1]);                      \
      pkfma(c, rp2, w2[s][2]); pkfma(c, rp3, w2[s][3]);                      \
      v[s] = c.x + c.y;                                                      \
    }                                                                        \
    _Pragma("unroll")                                                        \
    for (int s = 0; s < 8; ++s) v[s] += dpp_recv<0xB1>(v[s + 8]);            \
    _Pragma("unroll")                                                        \
    for (int s = 0; s < 4; ++s) v[s] += dpp_recv<0x4E>(v[s + 4]);            \
    _Pragma("unroll")                                                        \
    for (int s = 0; s < 2; ++s) v[s] += dpp_recv<0x128>(v[s + 2]);           \
    v[0] += SWZ(v[1], 0x401F);                                               \
    {                                                                        \
      float pa = v[0], pb = v[0];                                            \
      asm("v_permlane32_swap_b32 %0, %1" : "+v"(pa), "+v"(pb));              \
      v[0] = pa + pb;                                                        \
    }                                                                        \
    if (owner) {                                                             \
      float hn = fmaf(LEAK, h, u_c) + v[0];                                  \
      hn = fminf(fmaxf(hn, -CLAMP_V), CLAMP_V);                              \
      *ys_ptr = hn;                                                          \
      h = hn; u_c = u_n; u_n = u_pf;                                         \
    }                                                                        \
    ys_ptr += Bn * Hn;                                                       \
    u_ptr  += Bn * Hn;                                                       \
  }

  for (int tt = 0; tt < Tn; tt += 2) {
    { const int t = tt;     SCAN_STEP(0) }
    { const int t = tt + 1; SCAN_STEP(1) }
  }
#undef SCAN_STEP

  if (owner) out[(long)Bn * Tn * 2 + b * Hn + j_own] = h;
}

// ---------------------------------------------------------------------------
// G2 (+fused head): v = relu(ys @ W2^T + b2); y = v @ W3^T + b3;
// softmax/mix epilogue inline (k_head math verbatim) -> final probs to d_out.
// ---------------------------------------------------------------------------
__global__ __launch_bounds__(512) void g_out(
    const float* __restrict__ ys, const float* __restrict__ W2,
    const float* __restrict__ b2, const float* __restrict__ W3,
    const float* __restrict__ b3, const float* __restrict__ Qs,
    const float* __restrict__ reward, const float* __restrict__ mix_w,
    float* __restrict__ out)
{
  __shared__ short Ah[128*SA], Al[128*SA], Bh[256*SA], Bl[256*SA];
  __shared__ float b2_s[256];
  __shared__ float w3_s[512];
  const int tid = threadIdx.x;
  const int r0  = blockIdx.x * 128;

  if (tid < 256) b2_s[tid] = b2[tid];
  if (tid < 512) w3_s[tid] = W3[tid];

  const int w    = tid >> 6, lane = tid & 63;
  const int wm   = w >> 2, wn = w & 3;
  const int fr   = lane & 15, fk = lane >> 4;
  f32x4 acc[4][4];
  #pragma unroll
  for (int a = 0; a < 4; ++a)
    #pragma unroll
    for (int c = 0; c < 4; ++c) acc[a][c] = (f32x4){0.f, 0.f, 0.f, 0.f};

  __syncthreads();

  for (int ks = 0; ks < 8; ++ks) {
    const int k0 = ks * 32;
    if (ks) __syncthreads();
    for (int c = tid; c < 1024; c += 512) {
      int rr = c >> 3, kc = (c & 7) * 4;
      float4 f = *reinterpret_cast<const float4*>(&ys[(long)(r0 + rr) * Hn + k0 + kc]);
      short h0 = bf16_rne(f.x), h1 = bf16_rne(f.y), h2 = bf16_rne(f.z), h3 = bf16_rne(f.w);
      short l0 = bf16_rne(f.x - bf16_to_f(h0)), l1 = bf16_rne(f.y - bf16_to_f(h1));
      short l2 = bf16_rne(f.z - bf16_to_f(h2)), l3 = bf16_rne(f.w - bf16_to_f(h3));
      int off = rr * SA + kc;
      *reinterpret_cast<uint2*>(&Ah[off]) = make_uint2(pack2(h0, h1), pack2(h2, h3));
      *reinterpret_cast<uint2*>(&Al[off]) = make_uint2(pack2(l0, l1), pack2(l2, l3));
    }
    for (int c = tid; c < 2048; c += 512) {
      int n = c >> 3, kc = (c & 7) * 4;
      float4 f = *reinterpret_cast<const float4*>(&W2[n * 256 + k0 + kc]);
      short h0 = bf16_rne(f.x), h1 = bf16_rne(f.y), h2 = bf16_rne(f.z), h3 = bf16_rne(f.w);
      short l0 = bf16_rne(f.x - bf16_to_f(h0)), l1 = bf16_rne(f.y - bf16_to_f(h1));
      short l2 = bf16_rne(f.z - bf16_to_f(h2)), l3 = bf16_rne(f.w - bf16_to_f(h3));
      int off = n * SA + kc;
      *reinterpret_cast<uint2*>(&Bh[off]) = make_uint2(pack2(h0, h1), pack2(h2, h3));
      *reinterpret_cast<uint2*>(&Bl[off]) = make_uint2(pack2(l0, l1), pack2(l2, l3));
    }
    __syncthreads();
    short8 bhf[4], blf[4];
    #pragma unroll
    for (int nf = 0; nf < 4; ++nf) {
      const int brow = wn * 64 + nf * 16 + fr;
      bhf[nf] = *reinterpret_cast<const short8*>(&Bh[brow * SA + fk * 8]);
      blf[nf] = *reinterpret_cast<const short8*>(&Bl[brow * SA + fk * 8]);
    }
    #pragma unroll
    for (int mf = 0; mf < 4; ++mf) {
      const int arow = wm * 64 + mf * 16 + fr;
      short8 ah = *reinterpret_cast<const short8*>(&Ah[arow * SA + fk * 8]);
      short8 al = *reinterpret_cast<const short8*>(&Al[arow * SA + fk * 8]);
      #pragma unroll
      for (int nf = 0; nf < 4; ++nf) {
        acc[mf][nf] = __builtin_amdgcn_mfma_f32_16x16x32_bf16(ah, bhf[nf], acc[mf][nf], 0, 0, 0);
        acc[mf][nf] = __builtin_amdgcn_mfma_f32_16x16x32_bf16(ah, blf[nf], acc[mf][nf], 0, 0, 0);
        acc[mf][nf] = __builtin_amdgcn_mfma_f32_16x16x32_bf16(al, bhf[nf], acc[mf][nf], 0, 0, 0);
      }
    }
  }

  float yp[4][4][2];
  #pragma unroll
  for (int mf = 0; mf < 4; ++mf)
    #pragma unroll
    for (int j = 0; j < 4; ++j) { yp[mf][j][0] = 0.f; yp[mf][j][1] = 0.f; }

  #pragma unroll
  for (int mf = 0; mf < 4; ++mf)
    #pragma unroll
    for (int nf = 0; nf < 4; ++nf) {
      const int n = wn * 64 + nf * 16 + fr;
      const float b2v = b2_s[n];
      const float w30 = w3_s[n], w31 = w3_s[256 + n];
      #pragma unroll
      for (int j = 0; j < 4; ++j) {
        float v = fmaxf(acc[mf][nf][j] + b2v, 0.f);
        yp[mf][j][0] = fmaf(v, w30, yp[mf][j][0]);
        yp[mf][j][1] = fmaf(v, w31, yp[mf][j][1]);
      }
    }
  #pragma unroll
  for (int off = 1; off < 16; off <<= 1) {
    #pragma unroll
    for (int mf = 0; mf < 4; ++mf)
      #pragma unroll
      for (int j = 0; j < 4; ++j) {
        yp[mf][j][0] += __shfl_xor(yp[mf][j][0], off);
        yp[mf][j][1] += __shfl_xor(yp[mf][j][1], off);
      }
  }

  __syncthreads();
  float* yred = reinterpret_cast<float*>(Ah);   // [128][2][4 wn]
  if (fr == 0) {
    #pragma unroll
    for (int mf = 0; mf < 4; ++mf)
      #pragma unroll
      for (int j = 0; j < 4; ++j) {
        int rl = wm * 64 + mf * 16 + (lane >> 4) * 4 + j;
        yred[(rl * 2 + 0) * 4 + wn] = yp[mf][j][0];
        yred[(rl * 2 + 1) * 4 + wn] = yp[mf][j][1];
      }
  }
  __syncthreads();
  if (tid < 128) {
    const int rl = tid;
    const float* yr0 = &yred[(rl * 2 + 0) * 4];
    const float* yr1 = &yred[(rl * 2 + 1) * 4];
    float y0 = (yr0[0] + yr0[1]) + (yr0[2] + yr0[3]) + b3[0];
    float y1 = (yr1[0] + yr1[1]) + (yr1[2] + yr1[3]) + b3[1];
    int r = r0 + rl, b = r & 63, t = r >> 6;
    const long base = ((long)b * Tn + t) * 2;

    float z0 = (y0 == 0.f) ? EPS_V : 0.f;
    float z1 = (y1 == 0.f) ? EPS_V : 0.f;

    float m  = fmaxf(y0, y1);
    float e0 = expf(y0 - m), e1 = expf(y1 - m), es = e0 + e1;
    float sp0 = e0 / es, sp1 = e1 / es;

    float q0 = Qs[base], q1 = Qs[base + 1];
    float mq = fmaxf(q0, q1);
    float f0 = expf(q0 - mq), f1 = expf(q1 - mq), fs = f0 + f1;
    float sq0 = f0 / fs, sq1 = f1 / fs;

    int ri = (int)reward[base];
    float m0 = fminf(fmaxf(mix_w[ri * 2 + 0], -1.f), 1.f);
    float m1 = fminf(fmaxf(mix_w[ri * 2 + 1], -1.f), 1.f);
    float den = fabsf(m0) + fabsf(m1);
    float s0 = m0 / den, s1 = m1 / den;

    out[base]     = expf(s0 * logf(sp0 + z0) + s1 * logf(sq0 + z0));
    out[base + 1] = expf(s0 * logf(sp1 + z1) + s1 * logf(sq1 + z1));
  }
}

// ---------------------------------------------------------------------------
extern "C" void kernel_launch(void* const* d_in, const int* in_sizes, int n_in,
                              void* d_out, int out_size, void* d_ws, size_t ws_size,
                              hipStream_t stream)
{
  const float* state       = (const float*)d_in[0];
  const float* last_action = (const float*)d_in[1];
  const float* reward      = (const float*)d_in[2];
  const float* hidden_in   = (const float*)d_in[3];
  const float* W1          = (const float*)d_in[4];
  const float* b1          = (const float*)d_in[5];
  const float* Wih         = (const float*)d_in[6];
  const float* Whh_raw     = (const float*)d_in[7];
  const float* W2          = (const float*)d_in[8];
  const float* b2          = (const float*)d_in[9];
  const float* W3          = (const float*)d_in[10];
  const float* b3          = (const float*)d_in[11];
  const float* Qs          = (const float*)d_in[12];
  const float* mix_w       = (const float*)d_in[13];
  float* out = (float*)d_out;
  float* u   = (float*)d_ws;   // (T*B, H) fp32 = 128 MiB; ys overwrites in place

  const int nrows = Tn * Bn;                 // 131072
  g_u   <<<nrows / 128, 512, 0, stream>>>(reward, state, last_action, W1, b1, Wih, u);
  k_scan<<<Bn / 2,      1024, 0, stream>>>(Whh_raw, hidden_in, u, out);
  g_out <<<nrows / 128, 512, 0, stream>>>(u, W2, b2, W3, b3, Qs, reward, mix_w, out);
}

// Round 17
// 1453.487 us; speedup vs baseline: 7.6685x; 7.6685x over previous
//
#include <hip/hip_runtime.h>
#include <hip/hip_bf16.h>
#include <math.h>

#define Bn 64
#define Tn 2048
#define Hn 256

constexpr float LEAK    = 0.5f;     // 1 - 1/TAU
constexpr float NEGDIAG = -0.5f;    // -1/TAU
constexpr float CLAMP_V = 1000.0f;
constexpr float EPS_V   = 1e-4f;

typedef __attribute__((ext_vector_type(8))) short  short8;  // 8 bf16 (4 VGPR)
typedef __attribute__((ext_vector_type(4))) float  f32x4;
typedef __attribute__((ext_vector_type(2))) float  f32x2;

#define FAST_BARRIER() do {                                   \
    asm volatile("s_waitcnt lgkmcnt(0)" ::: "memory");        \
    __builtin_amdgcn_s_barrier();                             \
    asm volatile("" ::: "memory");                            \
  } while (0)

__device__ inline short bf16_rne(float x) {
  __hip_bfloat16 h = __float2bfloat16(x);
  return *reinterpret_cast<short*>(&h);
}
__device__ inline float bf16_to_f(short s) {
  union { unsigned u; float f; } c; c.u = ((unsigned)(unsigned short)s) << 16;
  return c.f;
}
__device__ inline unsigned pack2(short a, short b) {
  return (unsigned)(unsigned short)a | ((unsigned)(unsigned short)b << 16);
}
// packed dual fp32 FMA: a += x*y
__device__ inline void pkfma(f32x2& a, f32x2 x, f32x2 y) {
  asm("v_pk_fma_f32 %0, %1, %2, %0" : "+v"(a) : "v"(x), "v"(y));
}
#define SWZ(x, imm) __int_as_float(__builtin_amdgcn_ds_swizzle(__float_as_int(x), (imm)))

// DPP receive: value of `x` from the DPP-selected partner lane (VALU pipe)
template <int CTRL>
__device__ __forceinline__ float dpp_recv(float x) {
  return __int_as_float(
      __builtin_amdgcn_update_dpp(0, __float_as_int(x), CTRL, 0xF, 0xF, true));
}

// LDS row stride for bf16 tiles: 32 k + 8 pad = 40 shorts (80 B, 16B-multiple)
#define SA 40

// ---------------------------------------------------------------------------
// G1: u = relu(inp8 @ W1^T + b1) @ Wih^T, MFMA bf16 hi/lo. (passing, frozen)
// ---------------------------------------------------------------------------
__global__ __launch_bounds__(512) void g_u(
    const float* __restrict__ reward, const float* __restrict__ state,
    const float* __restrict__ last_action, const float* __restrict__ W1,
    const float* __restrict__ b1, const float* __restrict__ Wih,
    float* __restrict__ u)
{
  __shared__ short Ah[128*SA], Al[128*SA], Bh[256*SA], Bl[256*SA];
  __shared__ __align__(16) float inp_s[128][8];
  __shared__ __align__(16) float w1_s[256][8];
  __shared__ float b1_s[256];
  const int tid = threadIdx.x;
  const int r0  = blockIdx.x * 128;

  for (int idx = tid; idx < 2048; idx += 512) ((float*)w1_s)[idx] = W1[idx];
  if (tid < 256) b1_s[tid] = b1[tid];
  for (int idx = tid; idx < 1024; idx += 512) {
    int rr = idx >> 3, i = idx & 7;
    int r = r0 + rr, b = r & 63, t = r >> 6;
    long base = (long)b * Tn + t;
    float v;
    if (i < 2)      v = reward[base * 2 + i];
    else if (i < 6) v = state[base * 4 + (i - 2)];
    else            v = last_action[base * 2 + (i - 6)];
    inp_s[rr][i] = v;
  }

  const int w    = tid >> 6, lane = tid & 63;
  const int wm   = w >> 2, wn = w & 3;
  const int fr   = lane & 15, fk = lane >> 4;
  f32x4 acc[4][4];
  #pragma unroll
  for (int a = 0; a < 4; ++a)
    #pragma unroll
    for (int c = 0; c < 4; ++c) acc[a][c] = (f32x4){0.f, 0.f, 0.f, 0.f};

  __syncthreads();

  for (int ks = 0; ks < 8; ++ks) {
    const int k0 = ks * 32;
    if (ks) __syncthreads();
    for (int p = tid; p < 2048; p += 512) {
      int rr = p >> 4, kp = (p & 15) * 2;
      int k = k0 + kp;
      float4 iv0 = *reinterpret_cast<const float4*>(&inp_s[rr][0]);
      float4 iv1 = *reinterpret_cast<const float4*>(&inp_s[rr][4]);
      float4 wa0 = *reinterpret_cast<const float4*>(&w1_s[k][0]);
      float4 wa1 = *reinterpret_cast<const float4*>(&w1_s[k][4]);
      float4 wb0 = *reinterpret_cast<const float4*>(&w1_s[k+1][0]);
      float4 wb1 = *reinterpret_cast<const float4*>(&w1_s[k+1][4]);
      float s0 = b1_s[k], s1 = b1_s[k+1];
      s0 = fmaf(iv0.x, wa0.x, s0); s0 = fmaf(iv0.y, wa0.y, s0);
      s0 = fmaf(iv0.z, wa0.z, s0); s0 = fmaf(iv0.w, wa0.w, s0);
      s0 = fmaf(iv1.x, wa1.x, s0); s0 = fmaf(iv1.y, wa1.y, s0);
      s0 = fmaf(iv1.z, wa1.z, s0); s0 = fmaf(iv1.w, wa1.w, s0);
      s1 = fmaf(iv0.x, wb0.x, s1); s1 = fmaf(iv0.y, wb0.y, s1);
      s1 = fmaf(iv0.z, wb0.z, s1); s1 = fmaf(iv0.w, wb0.w, s1);
      s1 = fmaf(iv1.x, wb1.x, s1); s1 = fmaf(iv1.y, wb1.y, s1);
      s1 = fmaf(iv1.z, wb1.z, s1); s1 = fmaf(iv1.w, wb1.w, s1);
      float v0 = fmaxf(s0, 0.f), v1 = fmaxf(s1, 0.f);
      short h0 = bf16_rne(v0), h1 = bf16_rne(v1);
      short l0 = bf16_rne(v0 - bf16_to_f(h0)), l1 = bf16_rne(v1 - bf16_to_f(h1));
      int off = rr * SA + kp;
      *reinterpret_cast<unsigned*>(&Ah[off]) = pack2(h0, h1);
      *reinterpret_cast<unsigned*>(&Al[off]) = pack2(l0, l1);
    }
    for (int c = tid; c < 2048; c += 512) {
      int n = c >> 3, kc = (c & 7) * 4;
      float4 f = *reinterpret_cast<const float4*>(&Wih[n * 256 + k0 + kc]);
      short h0 = bf16_rne(f.x), h1 = bf16_rne(f.y), h2 = bf16_rne(f.z), h3 = bf16_rne(f.w);
      short l0 = bf16_rne(f.x - bf16_to_f(h0)), l1 = bf16_rne(f.y - bf16_to_f(h1));
      short l2 = bf16_rne(f.z - bf16_to_f(h2)), l3 = bf16_rne(f.w - bf16_to_f(h3));
      int off = n * SA + kc;
      *reinterpret_cast<uint2*>(&Bh[off]) = make_uint2(pack2(h0, h1), pack2(h2, h3));
      *reinterpret_cast<uint2*>(&Bl[off]) = make_uint2(pack2(l0, l1), pack2(l2, l3));
    }
    __syncthreads();
    short8 bhf[4], blf[4];
    #pragma unroll
    for (int nf = 0; nf < 4; ++nf) {
      const int brow = wn * 64 + nf * 16 + fr;
      bhf[nf] = *reinterpret_cast<const short8*>(&Bh[brow * SA + fk * 8]);
      blf[nf] = *reinterpret_cast<const short8*>(&Bl[brow * SA + fk * 8]);
    }
    #pragma unroll
    for (int mf = 0; mf < 4; ++mf) {
      const int arow = wm * 64 + mf * 16 + fr;
      short8 ah = *reinterpret_cast<const short8*>(&Ah[arow * SA + fk * 8]);
      short8 al = *reinterpret_cast<const short8*>(&Al[arow * SA + fk * 8]);
      #pragma unroll
      for (int nf = 0; nf < 4; ++nf) {
        acc[mf][nf] = __builtin_amdgcn_mfma_f32_16x16x32_bf16(ah, bhf[nf], acc[mf][nf], 0, 0, 0);
        acc[mf][nf] = __builtin_amdgcn_mfma_f32_16x16x32_bf16(ah, blf[nf], acc[mf][nf], 0, 0, 0);
        acc[mf][nf] = __builtin_amdgcn_mfma_f32_16x16x32_bf16(al, bhf[nf], acc[mf][nf], 0, 0, 0);
      }
    }
  }
  #pragma unroll
  for (int mf = 0; mf < 4; ++mf) {
    const int rbase = r0 + wm * 64 + mf * 16 + (lane >> 4) * 4;
    #pragma unroll
    for (int nf = 0; nf < 4; ++nf) {
      const int n = wn * 64 + nf * 16 + fr;
      #pragma unroll
      for (int j = 0; j < 4; ++j)
        u[(long)(rbase + j) * Hn + n] = acc[mf][nf][j];
    }
  }
}

// ---------------------------------------------------------------------------
// K2: r13's exact scan (passed 4x at ~1276us). 8 waves, XOR-keyed slots,
// verified reduce primitives only (quad_perm 0xB1/0x4E, row_ror:8,
// ds_swizzle 0x401F, permlane32_swap dup-sum). Frozen.
// ---------------------------------------------------------------------------
__global__ __launch_bounds__(512, 2) void k_scan(
    const float* __restrict__ Whh_raw, const float* __restrict__ hidden_in,
    float* __restrict__ ubuf, float* __restrict__ out)
{
  __shared__ __align__(16) float rh[2][256];
  const int tid = threadIdx.x;
  const int w = tid >> 6;                       // 0..7
  const int l = tid & 63;
  const int g = (l & 3) | ((l >> 1) & 0x1C);    // k-group: bits {0,1,3,4,5}
  const int o = (l >> 2) & 1;                   // output half
  const int b = blockIdx.x;
  const int key = ((g & 1) << 3) | ((g & 2) << 1) | ((g & 4) >> 1) | ((g & 8) >> 3);

  f32x2 w2[16][4];
  #pragma unroll
  for (int s = 0; s < 16; ++s) {
    const int j = (w << 5) + (o << 4) + (s ^ key);
    #pragma unroll
    for (int i = 0; i < 4; ++i) {
      const int k = (g << 3) + 2 * i;
      float a = Whh_raw[j * 256 + k];
      float c = Whh_raw[j * 256 + k + 1];
      if (k == j)     a = NEGDIAG;
      if (k + 1 == j) c = NEGDIAG;
      w2[s][i] = (f32x2){a, c};
    }
  }

  const bool owner = (l < 32);
  const int j_own = (w << 5) + (o << 4) + key;

  const int row  = g >> 2;
  const int srot = (((g & 3) << 3) + (row << 2)) & 31;
  const int rd1  = row * 32 + srot;
  const int rd2  = row * 32 + ((srot + 4) & 31);
  const int wrow = j_own >> 5;
  const int wr   = wrow * 32 + (((j_own & 31) + (wrow << 2)) & 31);

  float h = 0.f, u_c = 0.f, u_n = 0.f;
  if (owner) {
    h   = hidden_in[b * Hn + j_own];
    u_c = ubuf[(long)b * Hn + j_own];                    // u[t=0]
    u_n = ubuf[((long)Bn + b) * Hn + j_own];             // u[t=1]
  }
  const float* u_ptr  = ubuf + ((long)2 * Bn + b) * Hn + j_own;   // t = 2
  float*       ys_ptr = ubuf + (long)b * Hn + j_own;              // t = 0

#define SCAN_STEP(P)                                                         \
  {                                                                          \
    if (owner) rh[P][wr] = fmaxf(h, 0.f);                                    \
    FAST_BARRIER();                                                          \
    float u_pf = 0.f;                                                        \
    if (owner && t + 2 < Tn) u_pf = *u_ptr;                                  \
    const float4 ra = *reinterpret_cast<const float4*>(&rh[P][rd1]);         \
    const float4 rb = *reinterpret_cast<const float4*>(&rh[P][rd2]);         \
    const f32x2 rp0 = {ra.x, ra.y}, rp1 = {ra.z, ra.w};                      \
    const f32x2 rp2 = {rb.x, rb.y}, rp3 = {rb.z, rb.w};                      \
    float v[16];                                                             \
    _Pragma("unroll")                                                        \
    for (int s = 0; s < 16; ++s) {                                           \
      f32x2 c = {0.f, 0.f};                                                  \
      pkfma(c, rp0, w2[s][0]); pkfma(c, rp1, w2[s][1]);                      \
      pkfma(c, rp2, w2[s][2]); pkfma(c, rp3, w2[s][3]);                      \
      v[s] = c.x + c.y;                                                      \
    }                                                                        \
    _Pragma("unroll")                                                        \
    for (int s = 0; s < 8; ++s) v[s] += dpp_recv<0xB1>(v[s + 8]);            \
    _Pragma("unroll")                                                        \
    for (int s = 0; s < 4; ++s) v[s] += dpp_recv<0x4E>(v[s + 4]);            \
    _Pragma("unroll")                                                        \
    for (int s = 0; s < 2; ++s) v[s] += dpp_recv<0x128>(v[s + 2]);           \
    v[0] += SWZ(v[1], 0x401F);                                               \
    {                                                                        \
      float pa = v[0], pb = v[0];                                            \
      asm("v_permlane32_swap_b32 %0, %1" : "+v"(pa), "+v"(pb));              \
      v[0] = pa + pb;                                                        \
    }                                                                        \
    if (owner) {                                                             \
      float hn = fmaf(LEAK, h, u_c) + v[0];                                  \
      hn = fminf(fmaxf(hn, -CLAMP_V), CLAMP_V);                              \
      *ys_ptr = hn;                                                          \
      h = hn; u_c = u_n; u_n = u_pf;                                         \
    }                                                                        \
    ys_ptr += Bn * Hn;                                                       \
    u_ptr  += Bn * Hn;                                                       \
  }

  for (int tt = 0; tt < Tn; tt += 2) {
    #pragma unroll
    for (int s = 0; s < 16; ++s)
      asm volatile("" : "+v"(w2[s][0]), "+v"(w2[s][1]),
                        "+v"(w2[s][2]), "+v"(w2[s][3]));
    { const int t = tt;     SCAN_STEP(0) }
    { const int t = tt + 1; SCAN_STEP(1) }
  }
#undef SCAN_STEP

  if (owner) out[(long)Bn * Tn * 2 + b * Hn + j_own] = h;
}

// ---------------------------------------------------------------------------
// G2 (+fused head, verified r15): v = relu(ys @ W2^T + b2);
// y = v @ W3^T + b3; softmax/mix epilogue inline -> final probs to d_out.
// ---------------------------------------------------------------------------
__global__ __launch_bounds__(512) void g_out(
    const float* __restrict__ ys, const float* __restrict__ W2,
    const float* __restrict__ b2, const float* __restrict__ W3,
    const float* __restrict__ b3, const float* __restrict__ Qs,
    const float* __restrict__ reward, const float* __restrict__ mix_w,
    float* __restrict__ out)
{
  __shared__ short Ah[128*SA], Al[128*SA], Bh[256*SA], Bl[256*SA];
  __shared__ float b2_s[256];
  __shared__ float w3_s[512];
  const int tid = threadIdx.x;
  const int r0  = blockIdx.x * 128;

  if (tid < 256) b2_s[tid] = b2[tid];
  if (tid < 512) w3_s[tid] = W3[tid];

  const int w    = tid >> 6, lane = tid & 63;
  const int wm   = w >> 2, wn = w & 3;
  const int fr   = lane & 15, fk = lane >> 4;
  f32x4 acc[4][4];
  #pragma unroll
  for (int a = 0; a < 4; ++a)
    #pragma unroll
    for (int c = 0; c < 4; ++c) acc[a][c] = (f32x4){0.f, 0.f, 0.f, 0.f};

  __syncthreads();

  for (int ks = 0; ks < 8; ++ks) {
    const int k0 = ks * 32;
    if (ks) __syncthreads();
    for (int c = tid; c < 1024; c += 512) {
      int rr = c >> 3, kc = (c & 7) * 4;
      float4 f = *reinterpret_cast<const float4*>(&ys[(long)(r0 + rr) * Hn + k0 + kc]);
      short h0 = bf16_rne(f.x), h1 = bf16_rne(f.y), h2 = bf16_rne(f.z), h3 = bf16_rne(f.w);
      short l0 = bf16_rne(f.x - bf16_to_f(h0)), l1 = bf16_rne(f.y - bf16_to_f(h1));
      short l2 = bf16_rne(f.z - bf16_to_f(h2)), l3 = bf16_rne(f.w - bf16_to_f(h3));
      int off = rr * SA + kc;
      *reinterpret_cast<uint2*>(&Ah[off]) = make_uint2(pack2(h0, h1), pack2(h2, h3));
      *reinterpret_cast<uint2*>(&Al[off]) = make_uint2(pack2(l0, l1), pack2(l2, l3));
    }
    for (int c = tid; c < 2048; c += 512) {
      int n = c >> 3, kc = (c & 7) * 4;
      float4 f = *reinterpret_cast<const float4*>(&W2[n * 256 + k0 + kc]);
      short h0 = bf16_rne(f.x), h1 = bf16_rne(f.y), h2 = bf16_rne(f.z), h3 = bf16_rne(f.w);
      short l0 = bf16_rne(f.x - bf16_to_f(h0)), l1 = bf16_rne(f.y - bf16_to_f(h1));
      short l2 = bf16_rne(f.z - bf16_to_f(h2)), l3 = bf16_rne(f.w - bf16_to_f(h3));
      int off = n * SA + kc;
      *reinterpret_cast<uint2*>(&Bh[off]) = make_uint2(pack2(h0, h1), pack2(h2, h3));
      *reinterpret_cast<uint2*>(&Bl[off]) = make_uint2(pack2(l0, l1), pack2(l2, l3));
    }
    __syncthreads();
    short8 bhf[4], blf[4];
    #pragma unroll
    for (int nf = 0; nf < 4; ++nf) {
      const int brow = wn * 64 + nf * 16 + fr;
      bhf[nf] = *reinterpret_cast<const short8*>(&Bh[brow * SA + fk * 8]);
      blf[nf] = *reinterpret_cast<const short8*>(&Bl[brow * SA + fk * 8]);
    }
    #pragma unroll
    for (int mf = 0; mf < 4; ++mf) {
      const int arow = wm * 64 + mf * 16 + fr;
      short8 ah = *reinterpret_cast<const short8*>(&Ah[arow * SA + fk * 8]);
      short8 al = *reinterpret_cast<const short8*>(&Al[arow * SA + fk * 8]);
      #pragma unroll
      for (int nf = 0; nf < 4; ++nf) {
        acc[mf][nf] = __builtin_amdgcn_mfma_f32_16x16x32_bf16(ah, bhf[nf], acc[mf][nf], 0, 0, 0);
        acc[mf][nf] = __builtin_amdgcn_mfma_f32_16x16x32_bf16(ah, blf[nf], acc[mf][nf], 0, 0, 0);
        acc[mf][nf] = __builtin_amdgcn_mfma_f32_16x16x32_bf16(al, bhf[nf], acc[mf][nf], 0, 0, 0);
      }
    }
  }

  float yp[4][4][2];
  #pragma unroll
  for (int mf = 0; mf < 4; ++mf)
    #pragma unroll
    for (int j = 0; j < 4; ++j) { yp[mf][j][0] = 0.f; yp[mf][j][1] = 0.f; }

  #pragma unroll
  for (int mf = 0; mf < 4; ++mf)
    #pragma unroll
    for (int nf = 0; nf < 4; ++nf) {
      const int n = wn * 64 + nf * 16 + fr;
      const float b2v = b2_s[n];
      const float w30 = w3_s[n], w31 = w3_s[256 + n];
      #pragma unroll
      for (int j = 0; j < 4; ++j) {
        float v = fmaxf(acc[mf][nf][j] + b2v, 0.f);
        yp[mf][j][0] = fmaf(v, w30, yp[mf][j][0]);
        yp[mf][j][1] = fmaf(v, w31, yp[mf][j][1]);
      }
    }
  #pragma unroll
  for (int off = 1; off < 16; off <<= 1) {
    #pragma unroll
    for (int mf = 0; mf < 4; ++mf)
      #pragma unroll
      for (int j = 0; j < 4; ++j) {
        yp[mf][j][0] += __shfl_xor(yp[mf][j][0], off);
        yp[mf][j][1] += __shfl_xor(yp[mf][j][1], off);
      }
  }

  __syncthreads();
  float* yred = reinterpret_cast<float*>(Ah);   // [128][2][4 wn]
  if (fr == 0) {
    #pragma unroll
    for (int mf = 0; mf < 4; ++mf)
      #pragma unroll
      for (int j = 0; j < 4; ++j) {
        int rl = wm * 64 + mf * 16 + (lane >> 4) * 4 + j;
        yred[(rl * 2 + 0) * 4 + wn] = yp[mf][j][0];
        yred[(rl * 2 + 1) * 4 + wn] = yp[mf][j][1];
      }
  }
  __syncthreads();
  if (tid < 128) {
    const int rl = tid;
    const float* yr0 = &yred[(rl * 2 + 0) * 4];
    const float* yr1 = &yred[(rl * 2 + 1) * 4];
    float y0 = (yr0[0] + yr0[1]) + (yr0[2] + yr0[3]) + b3[0];
    float y1 = (yr1[0] + yr1[1]) + (yr1[2] + yr1[3]) + b3[1];
    int r = r0 + rl, b = r & 63, t = r >> 6;
    const long base = ((long)b * Tn + t) * 2;

    float z0 = (y0 == 0.f) ? EPS_V : 0.f;
    float z1 = (y1 == 0.f) ? EPS_V : 0.f;

    float m  = fmaxf(y0, y1);
    float e0 = expf(y0 - m), e1 = expf(y1 - m), es = e0 + e1;
    float sp0 = e0 / es, sp1 = e1 / es;

    float q0 = Qs[base], q1 = Qs[base + 1];
    float mq = fmaxf(q0, q1);
    float f0 = expf(q0 - mq), f1 = expf(q1 - mq), fs = f0 + f1;
    float sq0 = f0 / fs, sq1 = f1 / fs;

    int ri = (int)reward[base];
    float m0 = fminf(fmaxf(mix_w[ri * 2 + 0], -1.f), 1.f);
    float m1 = fminf(fmaxf(mix_w[ri * 2 + 1], -1.f), 1.f);
    float den = fabsf(m0) + fabsf(m1);
    float s0 = m0 / den, s1 = m1 / den;

    out[base]     = expf(s0 * logf(sp0 + z0) + s1 * logf(sq0 + z0));
    out[base + 1] = expf(s0 * logf(sp1 + z1) + s1 * logf(sq1 + z1));
  }
}

// ---------------------------------------------------------------------------
extern "C" void kernel_launch(void* const* d_in, const int* in_sizes, int n_in,
                              void* d_out, int out_size, void* d_ws, size_t ws_size,
                              hipStream_t stream)
{
  const float* state       = (const float*)d_in[0];
  const float* last_action = (const float*)d_in[1];
  const float* reward      = (const float*)d_in[2];
  const float* hidden_in   = (const float*)d_in[3];
  const float* W1          = (const float*)d_in[4];
  const float* b1          = (const float*)d_in[5];
  const float* Wih         = (const float*)d_in[6];
  const float* Whh_raw     = (const float*)d_in[7];
  const float* W2          = (const float*)d_in[8];
  const float* b2          = (const float*)d_in[9];
  const float* W3          = (const float*)d_in[10];
  const float* b3          = (const float*)d_in[11];
  const float* Qs          = (const float*)d_in[12];
  const float* mix_w       = (const float*)d_in[13];
  float* out = (float*)d_out;
  float* u   = (float*)d_ws;   // (T*B, H) fp32 = 128 MiB; ys overwrites in place

  const int nrows = Tn * Bn;                 // 131072
  g_u   <<<nrows / 128, 512, 0, stream>>>(reward, state, last_action, W1, b1, Wih, u);
  k_scan<<<Bn,           512, 0, stream>>>(Whh_raw, hidden_in, u, out);
  g_out <<<nrows / 128, 512, 0, stream>>>(u, W2, b2, W3, b3, Qs, reward, mix_w, out);
}